// Round 6
// baseline (281.976 us; speedup 1.0000x reference)
//
#include <hip/hip_runtime.h>
#include <hip/hip_bf16.h>

// Problem constants
#define BB 16
#define CC 64
#define HH 64
#define WW 64
#define QQ 8192
#define HID 256
#define KK 576            // C*9
#define HT 66             // H + 2 halo
#define FROW 264          // 257 channels padded to 264 (16B-aligned rows)

typedef short short8 __attribute__((ext_vector_type(8)));
typedef short sv4    __attribute__((ext_vector_type(4)));
typedef float f32x4  __attribute__((ext_vector_type(4)));

__device__ __forceinline__ short f2bf(float f) {
    union { float f; unsigned u; } v; v.f = f;
    unsigned r = v.u + 0x7fffu + ((v.u >> 16) & 1u);
    return (short)(r >> 16);
}
__device__ __forceinline__ float bf2f(short s) {
    union { unsigned u; float f; } v; v.u = ((unsigned)(unsigned short)s) << 16;
    return v.f;
}

// ---------------------------------------------------------------------------
// Kernel T+P fused: weight repack + feat transpose to channel-last bf16 halo.
// ---------------------------------------------------------------------------
__global__ __launch_bounds__(256) void prep_transpose_k(const float* __restrict__ feat,
                                                        const float* __restrict__ w2,
                                                        const float* __restrict__ w3,
                                                        const float* __restrict__ b3,
                                                        short* __restrict__ featT,
                                                        short* __restrict__ w3cT,
                                                        short* __restrict__ w2bT) {
    __shared__ float ftile[64][65];
    const int t = threadIdx.x;
    const int gidx = blockIdx.x * 256 + t;   // grid = 1056 wgs

    if (gidx < 272 * KK) {
        int n = gidx / KK, kk = gidx - n * KK;
        int pos = kk >> 6, c = kk & 63;
        float v = 0.f;
        if (n < 256)      v = w3[n * KK + c * 9 + pos];
        else if (n == 256) v = b3[c * 9 + pos];
        w3cT[gidx] = f2bf(v);
    }
    if (gidx < 256 * 256) {
        int n = gidx >> 8, k = gidx & 255;
        w2bT[gidx] = f2bf(w2[k * 256 + n]);
    }

    const int b = blockIdx.x / HT;
    const int yy = blockIdx.x - b * HT;
    short* out_row = featT + ((b * HT + yy) * HT) * 64;

    if (yy == 0 || yy == HT - 1) {
        for (int idx = t; idx < HT * 64; idx += 256) out_row[idx] = 0;
        return;
    }
    const int y = yy - 1;
    const float* src = feat + ((b * CC) * HH + y) * WW;
#pragma unroll
    for (int i = 0; i < 16; ++i) {
        int idx = i * 256 + t;
        int c = idx >> 6, x = idx & 63;
        ftile[c][x] = src[c * (HH * WW) + x];
    }
    if (t < 64) out_row[t] = 0;
    else if (t < 128) out_row[(HT - 1) * 64 + (t - 64)] = 0;
    __syncthreads();
#pragma unroll
    for (int i = 0; i < 16; ++i) {
        int idx = i * 256 + t;
        int x = idx >> 6, c = idx & 63;
        out_row[(x + 1) * 64 + c] = f2bf(ftile[c][x]);
    }
}

// ---------------------------------------------------------------------------
// Kernel C v4: implicit-GEMM conv. wg=(b,y): M=64, N=272, K=576 (18 steps).
//   bfr (global w3cT) double-buffered; af (LDS) just-in-time (12cyc ds_read
//   doesn't need double-buffer regs). launch_bounds(256,2): reg cap 256 ->
//   NO spill possible (R2/R5 lesson: spills cost GBs of scratch traffic).
// ---------------------------------------------------------------------------
#define SLAB_STRIDE 68   // 64 ch + 4 pad; 136 B rows
__global__ __launch_bounds__(256, 2) void conv_k(const short* __restrict__ featT,
                                                 const short* __restrict__ w3cT,
                                                 short* __restrict__ F) {
    __shared__ short lds[3 * HT * SLAB_STRIDE];   // 26,928 B; epilogue reuses
    const int t = threadIdx.x;
    const int wave = t >> 6, lane = t & 63, quad = lane >> 4, ln16 = lane & 15;
    const int b = blockIdx.x >> 6, y = blockIdx.x & 63;

    f32x4 acc[4][5];
#pragma unroll
    for (int a = 0; a < 4; ++a)
#pragma unroll
        for (int i = 0; i < 5; ++i) acc[a][i] = (f32x4){0.f, 0.f, 0.f, 0.f};

    short8 bfrB[2][5];
    auto load_bfr = [&](int buf, int st) {
        const int pos = st >> 1, ks = st & 1;
#pragma unroll
        for (int i = 0; i < 5; ++i) {
            int sub = (i < 4) ? (wave + 4 * i) : 16;
            int n = sub * 16 + ln16;
            bfrB[buf][i] = *(const short8*)(w3cT + n * KK + pos * 64 + ks * 32 + quad * 8);
        }
    };

    // Stage slab: featT rows y..y+2 contiguous (3*66*64 = 12672 shorts)
    const short* slabsrc = featT + b * (HT * HT * 64) + y * (HT * 64);
#pragma unroll
    for (int it = 0; it < 7; ++it) {
        int i = it * 256 + t;
        if (i < 1584) {
            short8 v = *(const short8*)(slabsrc + i * 8);
            int row = i >> 3, cs = (i & 7) * 8;
            short* d = &lds[row * SLAB_STRIDE + cs];
            *(sv4*)d       = __builtin_shufflevector(v, v, 0, 1, 2, 3);
            *(sv4*)(d + 4) = __builtin_shufflevector(v, v, 4, 5, 6, 7);
        }
    }
    load_bfr(0, 0);        // global prefetch overlaps the barrier drain
    __syncthreads();

#pragma unroll
    for (int st = 0; st < 18; ++st) {
        const int cur = st & 1;
        if (st < 17) load_bfr(cur ^ 1, st + 1);
        const int pos = st >> 1, ks = st & 1;
        const int di = pos / 3, dj = pos - di * 3;
        short8 af[4];
#pragma unroll
        for (int ms = 0; ms < 4; ++ms) {
            const short* ap = &lds[(di * HT + ms * 16 + ln16 + dj) * SLAB_STRIDE + ks * 32 + quad * 8];
            sv4 a0 = *(const sv4*)ap;
            sv4 a1 = *(const sv4*)(ap + 4);
            af[ms] = __builtin_shufflevector(a0, a1, 0, 1, 2, 3, 4, 5, 6, 7);
        }
#pragma unroll
        for (int i = 0; i < 5; ++i)
#pragma unroll
            for (int ms = 0; ms < 4; ++ms)
                acc[ms][i] = __builtin_amdgcn_mfma_f32_16x16x32_bf16(af[ms], bfrB[cur][i], acc[ms][i], 0, 0, 0);
    }

    // Epilogue: two 32-row halves through the slab LDS, full-line stores.
#pragma unroll
    for (int h = 0; h < 2; ++h) {
        __syncthreads();
#pragma unroll
        for (int i = 0; i < 5; ++i) {
            int sub = (i < 4) ? (wave + 4 * i) : 16;
            int n = sub * 16 + ln16;
            bool store = (i < 4) || (wave == 0 && n < FROW);
            if (store) {
#pragma unroll
                for (int ms2 = 0; ms2 < 2; ++ms2) {
                    int ms = h * 2 + ms2;
#pragma unroll
                    for (int r = 0; r < 4; ++r) {
                        int xl = ms2 * 16 + quad * 4 + r;
                        lds[xl * FROW + n] = f2bf(acc[ms][i][r]);
                    }
                }
            }
        }
        __syncthreads();
        short8* dst = (short8*)(F + ((long)(b * 64 + y) * 64 + h * 32) * FROW);
        const short8* src8 = (const short8*)lds;
        for (int idx = t; idx < (32 * FROW) / 8; idx += 256)
            dst[idx] = src8[idx];
    }
}

// ---------------------------------------------------------------------------
// Kernel M v4: ONE QUERY PER LANE. Zero LDS, zero barriers, fully
// wave-independent. Wave = 16 queries (quads redundantly compute coords/H1 —
// VALU was 15% busy, redundancy is free; spill-free register budget is not).
//   hf[s]   : H1^T B-fragment, lane = own query m, k = s*32+quad*8..+7
//   acc[i]  : D[n=i*16+quad*4+r][m=own query] = sum_s mfma(w2_frag, hf[s])
//   combine : per-lane dot with F[lin(own q)][n], reduce via 2 shfl_xor
// ---------------------------------------------------------------------------
__global__ __launch_bounds__(256, 2) void mlp_k(const float* __restrict__ coord,
                                                const float* __restrict__ cell,
                                                const float* __restrict__ w1,
                                                const float* __restrict__ b1,
                                                const float* __restrict__ b2v,
                                                const short* __restrict__ w2bT,
                                                const short* __restrict__ F,
                                                float* __restrict__ out) {
    const int t = threadIdx.x;
    const int wave = t >> 6, lane = t & 63, quad = lane >> 4, ln16 = lane & 15;
    const int q = blockIdx.x * 64 + wave * 16 + ln16;   // this lane's query
    const int b = blockIdx.x >> 7;                       // 128 wgs per batch

    // --- coords for own query (all 4 quads redundantly) ---
    const float2 cc = *(const float2*)(coord + q * 2);
    const float2 ce = *(const float2*)(cell + q * 2);
    const float coy = cc.x - ce.x * 0.5f, cox = cc.y - ce.y * 0.5f;
    const float cqy = fminf(fmaxf(coy + 1e-6f, -0.999999f), 0.999999f);
    const float cqx = fminf(fmaxf(cox + 1e-6f, -0.999999f), 0.999999f);
    int iy = (int)rintf(((cqy + 1.0f) * 64.0f - 1.0f) * 0.5f); iy = min(max(iy, 0), 63);
    int ix = (int)rintf(((cqx + 1.0f) * 64.0f - 1.0f) * 0.5f); ix = min(max(ix, 0), 63);
    const int lin = iy * 64 + ix;
    const float in0 = (coy - ((float)iy * (1.0f / 32.0f) - 1.0f)) * 32.0f;
    const float in1 = (cox - ((float)ix * (1.0f / 32.0f) - 1.0f)) * 32.0f;
    const float in2 = ce.x * 32.0f;

    // --- F prefetch: own row, own quad's n-slice; stays in flight through H1
    const short* Fr = F + ((long)b * 4096 + lin) * FROW + quad * 4;
    sv4 fv[16];
#pragma unroll
    for (int i = 0; i < 16; ++i) fv[i] = *(const sv4*)(Fr + i * 16);
    const float fbv = bf2f(F[((long)b * 4096 + lin) * FROW + 256]);   // b3 dot

    // --- H1 into registers: hf[s][jj] = relu(inp . w1[:, s*32+quad*8+jj] + b1)
    short8 hf[8];
#pragma unroll
    for (int s = 0; s < 8; ++s) {
        const int k0 = s * 32 + quad * 8;
        f32x4 wa0 = *(const f32x4*)(w1 + k0),       wa1 = *(const f32x4*)(w1 + k0 + 4);
        f32x4 wb0 = *(const f32x4*)(w1 + 256 + k0), wb1 = *(const f32x4*)(w1 + 256 + k0 + 4);
        f32x4 wc0 = *(const f32x4*)(w1 + 512 + k0), wc1 = *(const f32x4*)(w1 + 512 + k0 + 4);
        f32x4 bb0 = *(const f32x4*)(b1 + k0),       bb1 = *(const f32x4*)(b1 + k0 + 4);
#pragma unroll
        for (int jj = 0; jj < 4; ++jj) {
            float v0 = fmaf(in0, wa0[jj], fmaf(in1, wb0[jj], fmaf(in2, wc0[jj], bb0[jj])));
            float v1 = fmaf(in0, wa1[jj], fmaf(in1, wb1[jj], fmaf(in2, wc1[jj], bb1[jj])));
            hf[s][jj]     = f2bf(fmaxf(v0, 0.f));
            hf[s][jj + 4] = f2bf(fmaxf(v1, 0.f));
        }
    }

    // --- H2^T: acc[i] = sum_s mfma(w2bT n-subtile i, hf[s]) ---
    f32x4 acc[16];
#pragma unroll
    for (int i = 0; i < 16; ++i) acc[i] = (f32x4){0.f, 0.f, 0.f, 0.f};
#pragma unroll
    for (int s = 0; s < 8; ++s) {
#pragma unroll
        for (int i = 0; i < 16; ++i) {
            short8 wf = *(const short8*)(w2bT + (i * 16 + ln16) * 256 + s * 32 + quad * 8);
            acc[i] = __builtin_amdgcn_mfma_f32_16x16x32_bf16(wf, hf[s], acc[i], 0, 0, 0);
        }
    }

    // --- combine: pred[m] += relu(H2[n][m]+b2[n]) * F[lin][n], n=i*16+quad*4+r
    float part = 0.f;
#pragma unroll
    for (int i = 0; i < 16; ++i) {
        f32x4 b2q = *(const f32x4*)(b2v + i * 16 + quad * 4);
#pragma unroll
        for (int r = 0; r < 4; ++r)
            part = fmaf(fmaxf(acc[i][r] + b2q[r], 0.f), bf2f(fv[i][r]), part);
    }
    part += __shfl_xor(part, 16, 64);
    part += __shfl_xor(part, 32, 64);
    if (quad == 0) out[q] = part + fbv;
}

// ---------------------------------------------------------------------------
extern "C" void kernel_launch(void* const* d_in, const int* in_sizes, int n_in,
                              void* d_out, int out_size, void* d_ws, size_t ws_size,
                              hipStream_t stream) {
    const float* feat  = (const float*)d_in[0];
    const float* coord = (const float*)d_in[1];
    const float* cell  = (const float*)d_in[2];
    const float* w1    = (const float*)d_in[3];
    const float* b1    = (const float*)d_in[4];
    const float* w2    = (const float*)d_in[5];
    const float* b2    = (const float*)d_in[6];
    const float* w3    = (const float*)d_in[7];
    const float* b3    = (const float*)d_in[8];
    float* out = (float*)d_out;

    char* ws = (char*)d_ws;
    short* w3cT  = (short*)(ws);                       // 272*576*2      = 313,344
    short* w2bT  = (short*)(ws + 313344);              // 256*256*2      = 131,072
    short* featT = (short*)(ws + 444416);              // 16*66*66*64*2  = 8,921,088
    short* F     = (short*)(ws + 9365504);             // 16*4096*264*2  = 34,603,008
    (void)ws_size; (void)in_sizes; (void)n_in; (void)out_size;

    prep_transpose_k<<<BB * HT, 256, 0, stream>>>(feat, w2, w3, b3, featT, w3cT, w2bT);
    conv_k<<<BB * HH, 256, 0, stream>>>(featT, w3cT, F);
    mlp_k<<<(BB * QQ) / 64, 256, 0, stream>>>(coord, cell, w1, b1, b2, w2bT, F, out);
}

// Round 7
// 223.096 us; speedup vs baseline: 1.2639x; 1.2639x over previous
//
#include <hip/hip_runtime.h>
#include <hip/hip_bf16.h>

// Problem constants
#define BB 16
#define CC 64
#define HH 64
#define WW 64
#define QQ 8192
#define HID 256
#define KK 576            // C*9
#define HT 66             // H + 2 halo
#define FROW 264          // 257 channels padded to 264 (16B-aligned rows)

typedef short short8 __attribute__((ext_vector_type(8)));
typedef short sv4    __attribute__((ext_vector_type(4)));
typedef float f32x4  __attribute__((ext_vector_type(4)));

__device__ __forceinline__ short f2bf(float f) {
    union { float f; unsigned u; } v; v.f = f;
    unsigned r = v.u + 0x7fffu + ((v.u >> 16) & 1u);
    return (short)(r >> 16);
}
__device__ __forceinline__ float bf2f(short s) {
    union { unsigned u; float f; } v; v.u = ((unsigned)(unsigned short)s) << 16;
    return v.f;
}
// Barrier that only drains LDS (lgkmcnt) — does NOT force vmcnt(0), so global
// prefetches issued before it stay in flight.
__device__ __forceinline__ void barrier_lds() {
    asm volatile("s_waitcnt lgkmcnt(0)" ::: "memory");
    __builtin_amdgcn_s_barrier();
    asm volatile("" ::: "memory");
}

// ---------------------------------------------------------------------------
// Kernel T+P fused: weight repack + feat transpose to channel-last bf16 halo.
// ---------------------------------------------------------------------------
__global__ __launch_bounds__(256) void prep_transpose_k(const float* __restrict__ feat,
                                                        const float* __restrict__ w2,
                                                        const float* __restrict__ w3,
                                                        const float* __restrict__ b3,
                                                        short* __restrict__ featT,
                                                        short* __restrict__ w3cT,
                                                        short* __restrict__ w2bT) {
    __shared__ float ftile[64][65];
    const int t = threadIdx.x;
    const int gidx = blockIdx.x * 256 + t;   // grid = 1056 wgs

    if (gidx < 272 * KK) {
        int n = gidx / KK, kk = gidx - n * KK;
        int pos = kk >> 6, c = kk & 63;
        float v = 0.f;
        if (n < 256)      v = w3[n * KK + c * 9 + pos];
        else if (n == 256) v = b3[c * 9 + pos];
        w3cT[gidx] = f2bf(v);
    }
    if (gidx < 256 * 256) {
        int n = gidx >> 8, k = gidx & 255;
        w2bT[gidx] = f2bf(w2[k * 256 + n]);
    }

    const int b = blockIdx.x / HT;
    const int yy = blockIdx.x - b * HT;
    short* out_row = featT + ((b * HT + yy) * HT) * 64;

    if (yy == 0 || yy == HT - 1) {
        for (int idx = t; idx < HT * 64; idx += 256) out_row[idx] = 0;
        return;
    }
    const int y = yy - 1;
    const float* src = feat + ((b * CC) * HH + y) * WW;
#pragma unroll
    for (int i = 0; i < 16; ++i) {
        int idx = i * 256 + t;
        int c = idx >> 6, x = idx & 63;
        ftile[c][x] = src[c * (HH * WW) + x];
    }
    if (t < 64) out_row[t] = 0;
    else if (t < 128) out_row[(HT - 1) * 64 + (t - 64)] = 0;
    __syncthreads();
#pragma unroll
    for (int i = 0; i < 16; ++i) {
        int idx = i * 256 + t;
        int x = idx >> 6, c = idx & 63;
        out_row[(x + 1) * 64 + c] = f2bf(ftile[c][x]);
    }
}

// ---------------------------------------------------------------------------
// Kernel C v5: implicit-GEMM conv, M=32 pixels per wg (grid 2048) so ~4 wgs
// are resident per CU to overlap per-wg latency (R4/R6: grid 1024 -> only
// ~1.6 resident, 20% occupancy, MfmaUtil 14%).
//   wg=(b,y,xh): M=32 (x in [xh*32, xh*32+32)), N=272, K=576 (18 steps).
//   slab: 3 rows x 34 cols x 64 ch in LDS (13 KB); bfr double-buffered.
// ---------------------------------------------------------------------------
#define SLAB_STRIDE 68   // 64 ch + 4 pad
__global__ __launch_bounds__(256, 2) void conv_k(const short* __restrict__ featT,
                                                 const short* __restrict__ w3cT,
                                                 short* __restrict__ F) {
    __shared__ short lds[3 * 34 * SLAB_STRIDE];   // 6936 shorts = 13,872 B
    const int t = threadIdx.x;
    const int wave = t >> 6, lane = t & 63, quad = lane >> 4, ln16 = lane & 15;
    const int xh = blockIdx.x & 1;
    const int y = (blockIdx.x >> 1) & 63;
    const int b = blockIdx.x >> 7;

    f32x4 acc[2][5];
#pragma unroll
    for (int a = 0; a < 2; ++a)
#pragma unroll
        for (int i = 0; i < 5; ++i) acc[a][i] = (f32x4){0.f, 0.f, 0.f, 0.f};

    short8 bfrB[2][5];
    auto load_bfr = [&](int buf, int st) {
        const int pos = st >> 1, ks = st & 1;
#pragma unroll
        for (int i = 0; i < 5; ++i) {
            int sub = (i < 4) ? (wave + 4 * i) : 16;
            int n = sub * 16 + ln16;
            bfrB[buf][i] = *(const short8*)(w3cT + n * KK + pos * 64 + ks * 32 + quad * 8);
        }
    };

    // Stage slab: 3 rows (y..y+2) x 34 cols (xh*32 .. +33) x 64 ch
    const short* featb = featT + b * (HT * HT * 64);
    load_bfr(0, 0);        // prefetch overlaps staging + barrier
#pragma unroll
    for (int it = 0; it < 4; ++it) {
        int i = it * 256 + t;             // 816 chunks of 8 shorts
        if (i < 816) {
            int di = i / 272, rem = i - di * 272;     // 272 = 34 cols * 8 chunks
            int col = rem >> 3, cs = (rem & 7) * 8;
            short8 v = *(const short8*)(featb + ((y + di) * HT + xh * 32 + col) * 64 + cs);
            short* d = &lds[(di * 34 + col) * SLAB_STRIDE + cs];
            *(sv4*)d       = __builtin_shufflevector(v, v, 0, 1, 2, 3);
            *(sv4*)(d + 4) = __builtin_shufflevector(v, v, 4, 5, 6, 7);
        }
    }
    __syncthreads();

#pragma unroll
    for (int st = 0; st < 18; ++st) {
        const int cur = st & 1;
        if (st < 17) load_bfr(cur ^ 1, st + 1);
        const int pos = st >> 1, ks = st & 1;
        const int di = pos / 3, dj = pos - di * 3;
        short8 af[2];
#pragma unroll
        for (int ms = 0; ms < 2; ++ms) {
            const short* ap = &lds[(di * 34 + ms * 16 + ln16 + dj) * SLAB_STRIDE + ks * 32 + quad * 8];
            sv4 a0 = *(const sv4*)ap;
            sv4 a1 = *(const sv4*)(ap + 4);
            af[ms] = __builtin_shufflevector(a0, a1, 0, 1, 2, 3, 4, 5, 6, 7);
        }
#pragma unroll
        for (int i = 0; i < 5; ++i)
#pragma unroll
            for (int ms = 0; ms < 2; ++ms)
                acc[ms][i] = __builtin_amdgcn_mfma_f32_16x16x32_bf16(af[ms], bfrB[cur][i], acc[ms][i], 0, 0, 0);
    }

    // Epilogue: two 16-row halves through LDS (8448 B, fits in slab), then
    // full-line coalesced stores.
#pragma unroll
    for (int h = 0; h < 2; ++h) {
        __syncthreads();
#pragma unroll
        for (int i = 0; i < 5; ++i) {
            int sub = (i < 4) ? (wave + 4 * i) : 16;
            int n = sub * 16 + ln16;
            bool store = (i < 4) || (wave == 0 && n < FROW);
            if (store) {
#pragma unroll
                for (int r = 0; r < 4; ++r) {
                    int xl = quad * 4 + r;                 // local row 0..15
                    lds[xl * FROW + n] = f2bf(acc[h][i][r]);
                }
            }
        }
        __syncthreads();
        short8* dst = (short8*)(F + ((long)(b * 64 + y) * 64 + xh * 32 + h * 16) * FROW);
        const short8* src8 = (const short8*)lds;
        for (int idx = t; idx < (16 * FROW) / 8; idx += 256)
            dst[idx] = src8[idx];
    }
}

// ---------------------------------------------------------------------------
// Kernel M v5: R3 structure (waves share w2bT; H via LDS) with:
//   - H1 computed per-lane in regs (lane = query qbase+lane, wave = k-slice
//     [wave*64,wave*64+64)); written as 8 ds_write_b128 (was 64 b16 + barrier)
//   - wf (global) and hf (LDS) double-buffered one s-step ahead
//   - F gather AFTER the MFMA loop (frees 32 regs during loop)
//   - vmcnt-transparent barriers; (256,2) cap -> no spill possible
// ---------------------------------------------------------------------------
#define HSTRIDE 264
__global__ __launch_bounds__(256, 2) void mlp_k(const float* __restrict__ coord,
                                                const float* __restrict__ cell,
                                                const float* __restrict__ w1,
                                                const float* __restrict__ b1,
                                                const float* __restrict__ b2v,
                                                const short* __restrict__ w2bT,
                                                const short* __restrict__ F,
                                                float* __restrict__ out) {
    __shared__ short H_lds[64 * HSTRIDE];
    __shared__ float red_s[64][4];

    const int t = threadIdx.x;
    const int wave = t >> 6, lane = t & 63, quad = lane >> 4, ln16 = lane & 15;
    const int qbase = blockIdx.x * 64;
    const int b = qbase >> 13;            // Q = 8192

    // --- prefetch wf(s=0) and b2 quad (independent of everything) ---
    short8 wfB[2][4];
#pragma unroll
    for (int i = 0; i < 4; ++i)
        wfB[0][i] = *(const short8*)(w2bT + (wave * 64 + i * 16 + ln16) * 256 + quad * 8);
    f32x4 b2q[4];
#pragma unroll
    for (int i = 0; i < 4; ++i)
        b2q[i] = *(const f32x4*)(b2v + wave * 64 + i * 16 + quad * 4);

    // --- coords for own query (lane = query) ---
    const int g = qbase + lane;
    const float2 cc = *(const float2*)(coord + g * 2);
    const float2 ce = *(const float2*)(cell + g * 2);
    const float coy = cc.x - ce.x * 0.5f, cox = cc.y - ce.y * 0.5f;
    const float cqy = fminf(fmaxf(coy + 1e-6f, -0.999999f), 0.999999f);
    const float cqx = fminf(fmaxf(cox + 1e-6f, -0.999999f), 0.999999f);
    int iy = (int)rintf(((cqy + 1.0f) * 64.0f - 1.0f) * 0.5f); iy = min(max(iy, 0), 63);
    int ix = (int)rintf(((cqx + 1.0f) * 64.0f - 1.0f) * 0.5f); ix = min(max(ix, 0), 63);
    const int lin = iy * 64 + ix;
    const float in0 = (coy - ((float)iy * (1.0f / 32.0f) - 1.0f)) * 32.0f;
    const float in1 = (cox - ((float)ix * (1.0f / 32.0f) - 1.0f)) * 32.0f;
    const float in2 = ce.x * 32.0f;

    // --- H1 for own query, own wave's k-slice; w1 addresses wave-uniform ->
    //     scalar loads. 8 ds_write_b128 total.
    const int k0w = wave * 64;
#pragma unroll
    for (int c8 = 0; c8 < 8; ++c8) {
        const int k0 = k0w + c8 * 8;
        f32x4 wa0 = *(const f32x4*)(w1 + k0),       wa1 = *(const f32x4*)(w1 + k0 + 4);
        f32x4 wb0 = *(const f32x4*)(w1 + 256 + k0), wb1 = *(const f32x4*)(w1 + 256 + k0 + 4);
        f32x4 wc0 = *(const f32x4*)(w1 + 512 + k0), wc1 = *(const f32x4*)(w1 + 512 + k0 + 4);
        f32x4 bb0 = *(const f32x4*)(b1 + k0),       bb1 = *(const f32x4*)(b1 + k0 + 4);
        short8 hv;
#pragma unroll
        for (int jj = 0; jj < 4; ++jj) {
            float v0 = fmaf(in0, wa0[jj], fmaf(in1, wb0[jj], fmaf(in2, wc0[jj], bb0[jj])));
            float v1 = fmaf(in0, wa1[jj], fmaf(in1, wb1[jj], fmaf(in2, wc1[jj], bb1[jj])));
            hv[jj]     = f2bf(fmaxf(v0, 0.f));
            hv[jj + 4] = f2bf(fmaxf(v1, 0.f));
        }
        *(short8*)(&H_lds[lane * HSTRIDE + k0]) = hv;
    }
    barrier_lds();   // wf prefetch stays in flight (no vmcnt drain)

    // --- H2^T MFMA loop, wf+hf double-buffered ---
    f32x4 acc2[4][4];
#pragma unroll
    for (int i = 0; i < 4; ++i)
#pragma unroll
        for (int ms = 0; ms < 4; ++ms) acc2[i][ms] = (f32x4){0.f, 0.f, 0.f, 0.f};
    short8 hfB[2][4];
#pragma unroll
    for (int ms = 0; ms < 4; ++ms)
        hfB[0][ms] = *(const short8*)(&H_lds[(ms * 16 + ln16) * HSTRIDE + quad * 8]);
#pragma unroll
    for (int s = 0; s < 8; ++s) {
        const int cur = s & 1, nxt = cur ^ 1;
        if (s < 7) {
#pragma unroll
            for (int i = 0; i < 4; ++i)
                wfB[nxt][i] = *(const short8*)(w2bT + (wave * 64 + i * 16 + ln16) * 256 + (s + 1) * 32 + quad * 8);
#pragma unroll
            for (int ms = 0; ms < 4; ++ms)
                hfB[nxt][ms] = *(const short8*)(&H_lds[(ms * 16 + ln16) * HSTRIDE + (s + 1) * 32 + quad * 8]);
        }
#pragma unroll
        for (int i = 0; i < 4; ++i)
#pragma unroll
            for (int ms = 0; ms < 4; ++ms)
                acc2[i][ms] = __builtin_amdgcn_mfma_f32_16x16x32_bf16(wfB[cur][i], hfB[cur][ms], acc2[i][ms], 0, 0, 0);
    }

    // --- F gather (late; wf/hf regs dead by now) ---
    const short* Fb = F + (long)b * 4096 * FROW;
    sv4 fv[4][4];
#pragma unroll
    for (int ms = 0; ms < 4; ++ms) {
        int linm = __shfl(lin, ms * 16 + ln16, 64);
        const short* Fr = Fb + (long)linm * FROW + wave * 64 + quad * 4;
#pragma unroll
        for (int i = 0; i < 4; ++i) fv[ms][i] = *(const sv4*)(Fr + i * 16);
    }
    const float fbv = bf2f(Fb[(long)lin * FROW + 256]);

    // --- combine: pred[m] += relu(H2[n][m]+b2[n]) * F[lin[m]][n] ---
    float part[4] = {0.f, 0.f, 0.f, 0.f};
#pragma unroll
    for (int i = 0; i < 4; ++i)
#pragma unroll
        for (int ms = 0; ms < 4; ++ms)
#pragma unroll
            for (int r = 0; r < 4; ++r)
                part[ms] = fmaf(fmaxf(acc2[i][ms][r] + b2q[i][r], 0.f), bf2f(fv[ms][i][r]), part[ms]);
#pragma unroll
    for (int ms = 0; ms < 4; ++ms) {
        part[ms] += __shfl_xor(part[ms], 16, 64);
        part[ms] += __shfl_xor(part[ms], 32, 64);
    }
    if (quad == 0) {
#pragma unroll
        for (int ms = 0; ms < 4; ++ms) red_s[ms * 16 + ln16][wave] = part[ms];
    }
    barrier_lds();
    if (t < 64)
        out[qbase + t] = red_s[t][0] + red_s[t][1] + red_s[t][2] + red_s[t][3] + fbv;
}

// ---------------------------------------------------------------------------
extern "C" void kernel_launch(void* const* d_in, const int* in_sizes, int n_in,
                              void* d_out, int out_size, void* d_ws, size_t ws_size,
                              hipStream_t stream) {
    const float* feat  = (const float*)d_in[0];
    const float* coord = (const float*)d_in[1];
    const float* cell  = (const float*)d_in[2];
    const float* w1    = (const float*)d_in[3];
    const float* b1    = (const float*)d_in[4];
    const float* w2    = (const float*)d_in[5];
    const float* b2    = (const float*)d_in[6];
    const float* w3    = (const float*)d_in[7];
    const float* b3    = (const float*)d_in[8];
    float* out = (float*)d_out;

    char* ws = (char*)d_ws;
    short* w3cT  = (short*)(ws);                       // 272*576*2      = 313,344
    short* w2bT  = (short*)(ws + 313344);              // 256*256*2      = 131,072
    short* featT = (short*)(ws + 444416);              // 16*66*66*64*2  = 8,921,088
    short* F     = (short*)(ws + 9365504);             // 16*4096*264*2  = 34,603,008
    (void)ws_size; (void)in_sizes; (void)n_in; (void)out_size;

    prep_transpose_k<<<BB * HT, 256, 0, stream>>>(feat, w2, w3, b3, featT, w3cT, w2bT);
    conv_k<<<BB * HH * 2, 256, 0, stream>>>(featT, w3cT, F);
    mlp_k<<<(BB * QQ) / 64, 256, 0, stream>>>(coord, cell, w1, b1, b2, w2bT, F, out);
}

// Round 8
// 158.325 us; speedup vs baseline: 1.7810x; 1.4091x over previous
//
#include <hip/hip_runtime.h>
#include <hip/hip_bf16.h>

// Problem constants
#define BB 16
#define CC 64
#define HH 64
#define WW 64
#define QQ 8192
#define HID 256
#define KK 576            // C*9
#define HT 66             // H + 2 halo
#define FROW 264          // 257 channels padded to 264 (16B-aligned rows)

typedef short short8 __attribute__((ext_vector_type(8)));
typedef short sv4    __attribute__((ext_vector_type(4)));
typedef float f32x4  __attribute__((ext_vector_type(4)));

__device__ __forceinline__ short f2bf(float f) {
    union { float f; unsigned u; } v; v.f = f;
    unsigned r = v.u + 0x7fffu + ((v.u >> 16) & 1u);
    return (short)(r >> 16);
}
__device__ __forceinline__ float bf2f(short s) {
    union { unsigned u; float f; } v; v.u = ((unsigned)(unsigned short)s) << 16;
    return v.f;
}
// Async global->LDS DMA, 16B per lane. LDS dest is wave-uniform base +
// lane*16 (m104/m108); tracked by vmcnt, drained by __syncthreads.
__device__ __forceinline__ void glld16(const short* g, short* l) {
    __builtin_amdgcn_global_load_lds(
        (const __attribute__((address_space(1))) void*)g,
        (__attribute__((address_space(3))) void*)l, 16, 0, 0);
}

// ---------------------------------------------------------------------------
// Kernel T+P fused: feat transpose (channel-last bf16, zero halo) + weight
// repack into per-K-step contiguous DMA blocks:
//   w3cB[(kchunk)*2176 + n*8 + j] = w3k(n, kchunk*8+j)   (kchunk = kglob>>3)
//     where w3k(n, kk=pos*64+c) = w3[n][c*9+pos] | b3 | 0
//   w2cB[(kchunk)*2048 + n*8 + j] = w2[kchunk*8+j][n]
// ---------------------------------------------------------------------------
__global__ __launch_bounds__(256) void prep_transpose_k(const float* __restrict__ feat,
                                                        const float* __restrict__ w2,
                                                        const float* __restrict__ w3,
                                                        const float* __restrict__ b3,
                                                        short* __restrict__ featT,
                                                        short* __restrict__ w3cB,
                                                        short* __restrict__ w2cB) {
    __shared__ float ftile[64][65];
    const int t = threadIdx.x;
    const int gidx = blockIdx.x * 256 + t;   // grid = 1056 wgs

    if (gidx < 156672) {                      // 72 kchunks * 272 n * 8
        int kchunk = gidx / 2176;
        int rem = gidx - kchunk * 2176;
        int n = rem >> 3, j = rem & 7;
        int kglob = kchunk * 8 + j;
        int pos = kglob >> 6, c = kglob & 63;
        float v = 0.f;
        if (n < 256)      v = w3[n * KK + c * 9 + pos];
        else if (n == 256) v = b3[c * 9 + pos];
        w3cB[gidx] = f2bf(v);
    }
    if (gidx < 65536) {                       // 32 kchunks * 256 n * 8
        int kchunk = gidx >> 11;
        int rem = gidx & 2047;
        int n = rem >> 3, j = rem & 7;
        int k = kchunk * 8 + j;
        w2cB[gidx] = f2bf(w2[k * 256 + n]);
    }

    const int b = blockIdx.x / HT;
    const int yy = blockIdx.x - b * HT;
    short* out_row = featT + ((b * HT + yy) * HT) * 64;

    if (yy == 0 || yy == HT - 1) {
        for (int idx = t; idx < HT * 64; idx += 256) out_row[idx] = 0;
        return;
    }
    const int y = yy - 1;
    const float* src = feat + ((b * CC) * HH + y) * WW;
#pragma unroll
    for (int i = 0; i < 16; ++i) {
        int idx = i * 256 + t;
        int c = idx >> 6, x = idx & 63;
        ftile[c][x] = src[c * (HH * WW) + x];
    }
    if (t < 64) out_row[t] = 0;
    else if (t < 128) out_row[(HT - 1) * 64 + (t - 64)] = 0;
    __syncthreads();
#pragma unroll
    for (int i = 0; i < 16; ++i) {
        int idx = i * 256 + t;
        int x = idx >> 6, c = idx & 63;
        out_row[(x + 1) * 64 + c] = f2bf(ftile[c][x]);
    }
}

// ---------------------------------------------------------------------------
// Kernel C v6: m97-style K-loop. wg=(b,y): M=64, N=272, K=576 (18 steps).
//   Per step: DMA next B-tile (17.4 KB, global_load_lds x16B) into LDS
//   double-buffer while MFMAs consume current tile from LDS (ds_read_b128,
//   conflict-free layouts). One barrier per step drains the DMA.
//   A-slab (3x66x64, stride 72 -> 2-way bank alias = free, 16B aligned)
//   staged once. Epilogue through slab LDS in two 32-row halves.
// ---------------------------------------------------------------------------
#define SSTR 72   // slab row stride (shorts): 144B, 16B-aligned, free 2-way
__global__ __launch_bounds__(256, 2) void conv_k(const short* __restrict__ featT,
                                                 const short* __restrict__ w3cB,
                                                 short* __restrict__ F) {
    __shared__ short slab[3 * HT * SSTR];   // 14,256 shorts = 28,512 B
    __shared__ short Bb[2][8704];           // 2 x 17,408 B
    const int t = threadIdx.x;
    const int wave = t >> 6, lane = t & 63, quad = lane >> 4, ln16 = lane & 15;
    const int b = blockIdx.x >> 6, y = blockIdx.x & 63;

    f32x4 acc[4][5];
#pragma unroll
    for (int a = 0; a < 4; ++a)
#pragma unroll
        for (int i = 0; i < 5; ++i) acc[a][i] = (f32x4){0.f, 0.f, 0.f, 0.f};

    auto stageB = [&](int buf, int st) {
        const short* src = w3cB + st * 8704;
#pragma unroll
        for (int u = 0; u < 5; ++u) {
            int cidx = (u < 4) ? (u * 4 + wave) : 16;
            if (u < 4 || wave == 0)
                glld16(src + cidx * 512 + lane * 8, &Bb[buf][cidx * 512]);
        }
    };

    stageB(0, 0);   // DMA in flight during slab staging

    // Stage slab: featT rows y..y+2 contiguous (3*66*64 = 12672 shorts)
    const short* slabsrc = featT + b * (HT * HT * 64) + y * (HT * 64);
#pragma unroll
    for (int it = 0; it < 7; ++it) {
        int i = it * 256 + t;               // 1584 chunks of 8 shorts
        if (i < 1584) {
            short8 v = *(const short8*)(slabsrc + i * 8);
            int row = i >> 3, cs = (i & 7) * 8;
            *(short8*)(&slab[row * SSTR + cs]) = v;
        }
    }
    __syncthreads();   // drains slab stores (lgkm) + B DMA (vmcnt)

#pragma unroll
    for (int st = 0; st < 18; ++st) {
        const int cur = st & 1;
        if (st < 17) stageB(cur ^ 1, st + 1);
        const int pos = st >> 1, ks = st & 1;
        const int di = pos / 3, dj = pos - di * 3;
        short8 af[4];
#pragma unroll
        for (int ms = 0; ms < 4; ++ms)
            af[ms] = *(const short8*)(&slab[(di * HT + ms * 16 + ln16 + dj) * SSTR + ks * 32 + quad * 8]);
#pragma unroll
        for (int i = 0; i < 5; ++i) {
            int sub = (i < 4) ? (wave + 4 * i) : 16;
            short8 bf = *(const short8*)(&Bb[cur][(quad * 272 + sub * 16 + ln16) * 8]);
#pragma unroll
            for (int ms = 0; ms < 4; ++ms)
                acc[ms][i] = __builtin_amdgcn_mfma_f32_16x16x32_bf16(af[ms], bf, acc[ms][i], 0, 0, 0);
        }
        __syncthreads();   // reads of Bb[cur] done; next step's DMA may reuse it
    }

    // Epilogue: two 32-row halves through slab LDS, full-line stores.
#pragma unroll
    for (int h = 0; h < 2; ++h) {
#pragma unroll
        for (int i = 0; i < 5; ++i) {
            int sub = (i < 4) ? (wave + 4 * i) : 16;
            int n = sub * 16 + ln16;
            bool store = (i < 4) || (wave == 0 && n < FROW);
            if (store) {
#pragma unroll
                for (int ms2 = 0; ms2 < 2; ++ms2) {
                    int ms = h * 2 + ms2;
#pragma unroll
                    for (int r = 0; r < 4; ++r) {
                        int xl = ms2 * 16 + quad * 4 + r;   // local row 0..31
                        slab[xl * FROW + n] = f2bf(acc[ms][i][r]);
                    }
                }
            }
        }
        __syncthreads();
        short8* dst = (short8*)(F + ((long)(b * 64 + y) * 64 + h * 32) * FROW);
        const short8* src8 = (const short8*)slab;
#pragma unroll
        for (int it = 0; it < 5; ++it) {
            int idx = it * 256 + t;
            if (idx < (32 * FROW) / 8) dst[idx] = src8[idx];
        }
        __syncthreads();
    }
}

// ---------------------------------------------------------------------------
// Kernel M v6: R3/R5 skeleton + m97-style w2 staging.
//   - per-lane coords + H1 in regs, 8 ds_write_b128 into H_lds
//   - per s-step: DMA next 16 KB w2 tile into LDS double-buffer while MFMAs
//     consume current; wf/hf via conflict-free ds_read_b128
//   - transposed H2, register combine, late F gather
// ---------------------------------------------------------------------------
#define HSTRIDE 264
__global__ __launch_bounds__(256, 2) void mlp_k(const float* __restrict__ coord,
                                                const float* __restrict__ cell,
                                                const float* __restrict__ w1,
                                                const float* __restrict__ b1,
                                                const float* __restrict__ b2v,
                                                const short* __restrict__ w2cB,
                                                const short* __restrict__ F,
                                                float* __restrict__ out) {
    __shared__ short H_lds[64 * HSTRIDE];   // 33,792 B
    __shared__ short Wb[2][8192];           // 2 x 16,384 B
    __shared__ float red_s[64][4];

    const int t = threadIdx.x;
    const int wave = t >> 6, lane = t & 63, quad = lane >> 4, ln16 = lane & 15;
    const int qbase = blockIdx.x * 64;
    const int b = qbase >> 13;              // Q = 8192

    auto stageW = [&](int buf, int s) {
        const short* src = w2cB + s * 8192;
#pragma unroll
        for (int u = 0; u < 4; ++u) {
            int cidx = u * 4 + wave;
            glld16(src + cidx * 512 + lane * 8, &Wb[buf][cidx * 512]);
        }
    };

    stageW(0, 0);   // DMA in flight through coord + H1 compute

    // --- coords for own query (lane = query) ---
    const int g = qbase + lane;
    const float2 cc = *(const float2*)(coord + g * 2);
    const float2 ce = *(const float2*)(cell + g * 2);
    const float coy = cc.x - ce.x * 0.5f, cox = cc.y - ce.y * 0.5f;
    const float cqy = fminf(fmaxf(coy + 1e-6f, -0.999999f), 0.999999f);
    const float cqx = fminf(fmaxf(cox + 1e-6f, -0.999999f), 0.999999f);
    int iy = (int)rintf(((cqy + 1.0f) * 64.0f - 1.0f) * 0.5f); iy = min(max(iy, 0), 63);
    int ix = (int)rintf(((cqx + 1.0f) * 64.0f - 1.0f) * 0.5f); ix = min(max(ix, 0), 63);
    const int lin = iy * 64 + ix;
    const float in0 = (coy - ((float)iy * (1.0f / 32.0f) - 1.0f)) * 32.0f;
    const float in1 = (cox - ((float)ix * (1.0f / 32.0f) - 1.0f)) * 32.0f;
    const float in2 = ce.x * 32.0f;

    // --- H1 for own query, own wave's k-slice [wave*64, wave*64+64) ---
    const int k0w = wave * 64;
#pragma unroll
    for (int c8 = 0; c8 < 8; ++c8) {
        const int k0 = k0w + c8 * 8;
        f32x4 wa0 = *(const f32x4*)(w1 + k0),       wa1 = *(const f32x4*)(w1 + k0 + 4);
        f32x4 wb0 = *(const f32x4*)(w1 + 256 + k0), wb1 = *(const f32x4*)(w1 + 256 + k0 + 4);
        f32x4 wc0 = *(const f32x4*)(w1 + 512 + k0), wc1 = *(const f32x4*)(w1 + 512 + k0 + 4);
        f32x4 bb0 = *(const f32x4*)(b1 + k0),       bb1 = *(const f32x4*)(b1 + k0 + 4);
        short8 hv;
#pragma unroll
        for (int jj = 0; jj < 4; ++jj) {
            float v0 = fmaf(in0, wa0[jj], fmaf(in1, wb0[jj], fmaf(in2, wc0[jj], bb0[jj])));
            float v1 = fmaf(in0, wa1[jj], fmaf(in1, wb1[jj], fmaf(in2, wc1[jj], bb1[jj])));
            hv[jj]     = f2bf(fmaxf(v0, 0.f));
            hv[jj + 4] = f2bf(fmaxf(v1, 0.f));
        }
        *(short8*)(&H_lds[lane * HSTRIDE + k0]) = hv;
    }
    f32x4 b2q[4];
#pragma unroll
    for (int i = 0; i < 4; ++i)
        b2q[i] = *(const f32x4*)(b2v + wave * 64 + i * 16 + quad * 4);
    __syncthreads();   // drains H writes (lgkm) + Wb(0) DMA (vmcnt)

    // --- H2^T MFMA loop ---
    f32x4 acc2[4][4];
#pragma unroll
    for (int i = 0; i < 4; ++i)
#pragma unroll
        for (int ms = 0; ms < 4; ++ms) acc2[i][ms] = (f32x4){0.f, 0.f, 0.f, 0.f};
#pragma unroll
    for (int s = 0; s < 8; ++s) {
        const int cur = s & 1;
        if (s < 7) stageW(cur ^ 1, s + 1);
        short8 wf[4], hf[4];
#pragma unroll
        for (int i = 0; i < 4; ++i)
            wf[i] = *(const short8*)(&Wb[cur][(quad * 256 + wave * 64 + i * 16 + ln16) * 8]);
#pragma unroll
        for (int ms = 0; ms < 4; ++ms)
            hf[ms] = *(const short8*)(&H_lds[(ms * 16 + ln16) * HSTRIDE + s * 32 + quad * 8]);
#pragma unroll
        for (int i = 0; i < 4; ++i)
#pragma unroll
            for (int ms = 0; ms < 4; ++ms)
                acc2[i][ms] = __builtin_amdgcn_mfma_f32_16x16x32_bf16(wf[i], hf[ms], acc2[i][ms], 0, 0, 0);
        __syncthreads();
    }

    // --- F gather (late) ---
    const short* Fb = F + (long)b * 4096 * FROW;
    sv4 fv[4][4];
#pragma unroll
    for (int ms = 0; ms < 4; ++ms) {
        int linm = __shfl(lin, ms * 16 + ln16, 64);
        const short* Fr = Fb + (long)linm * FROW + wave * 64 + quad * 4;
#pragma unroll
        for (int i = 0; i < 4; ++i) fv[ms][i] = *(const sv4*)(Fr + i * 16);
    }
    const float fbv = bf2f(Fb[(long)lin * FROW + 256]);

    // --- combine: pred[m] += relu(H2[n][m]+b2[n]) * F[lin[m]][n] ---
    float part[4] = {0.f, 0.f, 0.f, 0.f};
#pragma unroll
    for (int i = 0; i < 4; ++i)
#pragma unroll
        for (int ms = 0; ms < 4; ++ms)
#pragma unroll
            for (int r = 0; r < 4; ++r)
                part[ms] = fmaf(fmaxf(acc2[i][ms][r] + b2q[i][r], 0.f), bf2f(fv[ms][i][r]), part[ms]);
#pragma unroll
    for (int ms = 0; ms < 4; ++ms) {
        part[ms] += __shfl_xor(part[ms], 16, 64);
        part[ms] += __shfl_xor(part[ms], 32, 64);
    }
    if (quad == 0) {
#pragma unroll
        for (int ms = 0; ms < 4; ++ms) red_s[ms * 16 + ln16][wave] = part[ms];
    }
    __syncthreads();
    if (t < 64)
        out[qbase + t] = red_s[t][0] + red_s[t][1] + red_s[t][2] + red_s[t][3] + fbv;
}

// ---------------------------------------------------------------------------
extern "C" void kernel_launch(void* const* d_in, const int* in_sizes, int n_in,
                              void* d_out, int out_size, void* d_ws, size_t ws_size,
                              hipStream_t stream) {
    const float* feat  = (const float*)d_in[0];
    const float* coord = (const float*)d_in[1];
    const float* cell  = (const float*)d_in[2];
    const float* w1    = (const float*)d_in[3];
    const float* b1    = (const float*)d_in[4];
    const float* w2    = (const float*)d_in[5];
    const float* b2    = (const float*)d_in[6];
    const float* w3    = (const float*)d_in[7];
    const float* b3    = (const float*)d_in[8];
    float* out = (float*)d_out;

    char* ws = (char*)d_ws;
    short* w3cB  = (short*)(ws);                       // 72*2176*2      = 313,344
    short* w2cB  = (short*)(ws + 313344);              // 32*2048*2      = 131,072
    short* featT = (short*)(ws + 444416);              // 16*66*66*64*2  = 8,921,088
    short* F     = (short*)(ws + 9365504);             // 16*4096*264*2  = 34,603,008
    (void)ws_size; (void)in_sizes; (void)n_in; (void)out_size;

    prep_transpose_k<<<BB * HT, 256, 0, stream>>>(feat, w2, w3, b3, featT, w3cB, w2cB);
    conv_k<<<BB * HH, 256, 0, stream>>>(featT, w3cB, F);
    mlp_k<<<(BB * QQ) / 64, 256, 0, stream>>>(coord, cell, w1, b1, b2, w2cB, F, out);
}

// Round 9
// 157.678 us; speedup vs baseline: 1.7883x; 1.0041x over previous
//
#include <hip/hip_runtime.h>
#include <hip/hip_bf16.h>

// Problem constants
#define BB 16
#define CC 64
#define HH 64
#define WW 64
#define QQ 8192
#define HID 256
#define KK 576            // C*9
#define HT 66             // H + 2 halo
#define FROW 264          // 257 channels padded to 264 (16B-aligned rows)

typedef short short8 __attribute__((ext_vector_type(8)));
typedef short sv4    __attribute__((ext_vector_type(4)));
typedef float f32x4  __attribute__((ext_vector_type(4)));

__device__ __forceinline__ short f2bf(float f) {
    union { float f; unsigned u; } v; v.f = f;
    unsigned r = v.u + 0x7fffu + ((v.u >> 16) & 1u);
    return (short)(r >> 16);
}
__device__ __forceinline__ float bf2f(short s) {
    union { unsigned u; float f; } v; v.u = ((unsigned)(unsigned short)s) << 16;
    return v.f;
}
// Barrier that only drains LDS (lgkmcnt) — does NOT force vmcnt(0).
__device__ __forceinline__ void barrier_lds() {
    asm volatile("s_waitcnt lgkmcnt(0)" ::: "memory");
    __builtin_amdgcn_s_barrier();
    asm volatile("" ::: "memory");
}
// Async global->LDS DMA, 16B per lane. LDS dest is wave-uniform base +
// lane*16; tracked by vmcnt, drained by __syncthreads.
__device__ __forceinline__ void glld16(const short* g, short* l) {
    __builtin_amdgcn_global_load_lds(
        (const __attribute__((address_space(1))) void*)g,
        (__attribute__((address_space(3))) void*)l, 16, 0, 0);
}

// ---------------------------------------------------------------------------
// Kernel T+P fused: feat transpose (channel-last bf16, zero halo) + weight
// repack into per-K-step contiguous DMA blocks:
//   w3cB[(kchunk)*2176 + n*8 + j] = w3k(n, kchunk*8+j)   (kchunk = kglob>>3)
//   w2cB[(kchunk)*2048 + n*8 + j] = w2[kchunk*8+j][n]
// ---------------------------------------------------------------------------
__global__ __launch_bounds__(256) void prep_transpose_k(const float* __restrict__ feat,
                                                        const float* __restrict__ w2,
                                                        const float* __restrict__ w3,
                                                        const float* __restrict__ b3,
                                                        short* __restrict__ featT,
                                                        short* __restrict__ w3cB,
                                                        short* __restrict__ w2cB) {
    __shared__ float ftile[64][65];
    const int t = threadIdx.x;
    const int gidx = blockIdx.x * 256 + t;   // grid = 1056 wgs

    if (gidx < 156672) {                      // 72 kchunks * 272 n * 8
        int kchunk = gidx / 2176;
        int rem = gidx - kchunk * 2176;
        int n = rem >> 3, j = rem & 7;
        int kglob = kchunk * 8 + j;
        int pos = kglob >> 6, c = kglob & 63;
        float v = 0.f;
        if (n < 256)      v = w3[n * KK + c * 9 + pos];
        else if (n == 256) v = b3[c * 9 + pos];
        w3cB[gidx] = f2bf(v);
    }
    if (gidx < 65536) {                       // 32 kchunks * 256 n * 8
        int kchunk = gidx >> 11;
        int rem = gidx & 2047;
        int n = rem >> 3, j = rem & 7;
        int k = kchunk * 8 + j;
        w2cB[gidx] = f2bf(w2[k * 256 + n]);
    }

    const int b = blockIdx.x / HT;
    const int yy = blockIdx.x - b * HT;
    short* out_row = featT + ((b * HT + yy) * HT) * 64;

    if (yy == 0 || yy == HT - 1) {
        for (int idx = t; idx < HT * 64; idx += 256) out_row[idx] = 0;
        return;
    }
    const int y = yy - 1;
    const float* src = feat + ((b * CC) * HH + y) * WW;
#pragma unroll
    for (int i = 0; i < 16; ++i) {
        int idx = i * 256 + t;
        int c = idx >> 6, x = idx & 63;
        ftile[c][x] = src[c * (HH * WW) + x];
    }
    if (t < 64) out_row[t] = 0;
    else if (t < 128) out_row[(HT - 1) * 64 + (t - 64)] = 0;
    __syncthreads();
#pragma unroll
    for (int i = 0; i < 16; ++i) {
        int idx = i * 256 + t;
        int x = idx >> 6, c = idx & 63;
        out_row[(x + 1) * 64 + c] = f2bf(ftile[c][x]);
    }
}

// ---------------------------------------------------------------------------
// Kernel C v6 (unchanged from R8 — proven): m97-style K-loop.
//   wg=(b,y): M=64, N=272, K=576 (18 steps). Per step: DMA next B-tile
//   (17.4 KB) into LDS double-buffer while MFMAs consume current tile.
// ---------------------------------------------------------------------------
#define SSTR 72   // slab row stride (shorts): 144B, 16B-aligned, free 2-way
__global__ __launch_bounds__(256, 2) void conv_k(const short* __restrict__ featT,
                                                 const short* __restrict__ w3cB,
                                                 short* __restrict__ F) {
    __shared__ short slab[3 * HT * SSTR];   // 14,256 shorts = 28,512 B
    __shared__ short Bb[2][8704];           // 2 x 17,408 B
    const int t = threadIdx.x;
    const int wave = t >> 6, lane = t & 63, quad = lane >> 4, ln16 = lane & 15;
    const int b = blockIdx.x >> 6, y = blockIdx.x & 63;

    f32x4 acc[4][5];
#pragma unroll
    for (int a = 0; a < 4; ++a)
#pragma unroll
        for (int i = 0; i < 5; ++i) acc[a][i] = (f32x4){0.f, 0.f, 0.f, 0.f};

    auto stageB = [&](int buf, int st) {
        const short* src = w3cB + st * 8704;
#pragma unroll
        for (int u = 0; u < 5; ++u) {
            int cidx = (u < 4) ? (u * 4 + wave) : 16;
            if (u < 4 || wave == 0)
                glld16(src + cidx * 512 + lane * 8, &Bb[buf][cidx * 512]);
        }
    };

    stageB(0, 0);   // DMA in flight during slab staging

    const short* slabsrc = featT + b * (HT * HT * 64) + y * (HT * 64);
#pragma unroll
    for (int it = 0; it < 7; ++it) {
        int i = it * 256 + t;               // 1584 chunks of 8 shorts
        if (i < 1584) {
            short8 v = *(const short8*)(slabsrc + i * 8);
            int row = i >> 3, cs = (i & 7) * 8;
            *(short8*)(&slab[row * SSTR + cs]) = v;
        }
    }
    __syncthreads();   // drains slab stores (lgkm) + B DMA (vmcnt)

#pragma unroll
    for (int st = 0; st < 18; ++st) {
        const int cur = st & 1;
        if (st < 17) stageB(cur ^ 1, st + 1);
        const int pos = st >> 1, ks = st & 1;
        const int di = pos / 3, dj = pos - di * 3;
        short8 af[4];
#pragma unroll
        for (int ms = 0; ms < 4; ++ms)
            af[ms] = *(const short8*)(&slab[(di * HT + ms * 16 + ln16 + dj) * SSTR + ks * 32 + quad * 8]);
#pragma unroll
        for (int i = 0; i < 5; ++i) {
            int sub = (i < 4) ? (wave + 4 * i) : 16;
            short8 bf = *(const short8*)(&Bb[cur][(quad * 272 + sub * 16 + ln16) * 8]);
#pragma unroll
            for (int ms = 0; ms < 4; ++ms)
                acc[ms][i] = __builtin_amdgcn_mfma_f32_16x16x32_bf16(af[ms], bf, acc[ms][i], 0, 0, 0);
        }
        __syncthreads();
    }

#pragma unroll
    for (int h = 0; h < 2; ++h) {
#pragma unroll
        for (int i = 0; i < 5; ++i) {
            int sub = (i < 4) ? (wave + 4 * i) : 16;
            int n = sub * 16 + ln16;
            bool store = (i < 4) || (wave == 0 && n < FROW);
            if (store) {
#pragma unroll
                for (int ms2 = 0; ms2 < 2; ++ms2) {
                    int ms = h * 2 + ms2;
#pragma unroll
                    for (int r = 0; r < 4; ++r) {
                        int xl = ms2 * 16 + quad * 4 + r;   // local row 0..31
                        slab[xl * FROW + n] = f2bf(acc[ms][i][r]);
                    }
                }
            }
        }
        __syncthreads();
        short8* dst = (short8*)(F + ((long)(b * 64 + y) * 64 + h * 32) * FROW);
        const short8* src8 = (const short8*)slab;
#pragma unroll
        for (int it = 0; it < 5; ++it) {
            int idx = it * 256 + t;
            if (idx < (32 * FROW) / 8) dst[idx] = src8[idx];
        }
        __syncthreads();
    }
}

// ---------------------------------------------------------------------------
// Kernel M v7: v6 + K-SPLIT H buffer for 3 wg/CU occupancy.
//   H2's s-loop consumes k<128 in s=0..3 and k>=128 in s=4..7, so H lives in
//   a HALF-K LDS buffer (64 x 136 = 17.4 KB instead of 33.8 KB):
//     waves 0/1 (k-slices 0..127) write before the loop;
//     waves 2/3 hold their H1 in 32 regs and write at the s=3 barrier
//     (which already exists to drain DMA tile 4 — only +1 cheap lgkm barrier).
//   LDS 67.6 -> 51.2 KB => 3 wg/CU (was 2). Double-buffered w2 DMA kept.
// ---------------------------------------------------------------------------
#define HSPLIT 136   // 272B rows: 16B-aligned for ds b128
__global__ __launch_bounds__(256, 2) void mlp_k(const float* __restrict__ coord,
                                                const float* __restrict__ cell,
                                                const float* __restrict__ w1,
                                                const float* __restrict__ b1,
                                                const float* __restrict__ b2v,
                                                const short* __restrict__ w2cB,
                                                const short* __restrict__ F,
                                                float* __restrict__ out) {
    __shared__ short Hh[64 * HSPLIT];       // 17,408 B (half-K)
    __shared__ short Wb[2][8192];           // 32,768 B
    __shared__ float red_s[64][4];          // 1,024 B

    const int t = threadIdx.x;
    const int wave = t >> 6, lane = t & 63, quad = lane >> 4, ln16 = lane & 15;
    const int qbase = blockIdx.x * 64;
    const int b = qbase >> 13;              // Q = 8192

    auto stageW = [&](int buf, int s) {
        const short* src = w2cB + s * 8192;
#pragma unroll
        for (int u = 0; u < 4; ++u) {
            int cidx = u * 4 + wave;
            glld16(src + cidx * 512 + lane * 8, &Wb[buf][cidx * 512]);
        }
    };

    stageW(0, 0);   // DMA in flight through coord + H1 compute

    // --- coords for own query (lane = query) ---
    const int g = qbase + lane;
    const float2 cc = *(const float2*)(coord + g * 2);
    const float2 ce = *(const float2*)(cell + g * 2);
    const float coy = cc.x - ce.x * 0.5f, cox = cc.y - ce.y * 0.5f;
    const float cqy = fminf(fmaxf(coy + 1e-6f, -0.999999f), 0.999999f);
    const float cqx = fminf(fmaxf(cox + 1e-6f, -0.999999f), 0.999999f);
    int iy = (int)rintf(((cqy + 1.0f) * 64.0f - 1.0f) * 0.5f); iy = min(max(iy, 0), 63);
    int ix = (int)rintf(((cqx + 1.0f) * 64.0f - 1.0f) * 0.5f); ix = min(max(ix, 0), 63);
    const int lin = iy * 64 + ix;
    const float in0 = (coy - ((float)iy * (1.0f / 32.0f) - 1.0f)) * 32.0f;
    const float in1 = (cox - ((float)ix * (1.0f / 32.0f) - 1.0f)) * 32.0f;
    const float in2 = ce.x * 32.0f;

    // --- H1 for own query, own wave's k-slice [wave*64, wave*64+64) -> regs
    short8 hv[8];
    const int k0w = wave * 64;
#pragma unroll
    for (int c8 = 0; c8 < 8; ++c8) {
        const int k0 = k0w + c8 * 8;
        f32x4 wa0 = *(const f32x4*)(w1 + k0),       wa1 = *(const f32x4*)(w1 + k0 + 4);
        f32x4 wb0 = *(const f32x4*)(w1 + 256 + k0), wb1 = *(const f32x4*)(w1 + 256 + k0 + 4);
        f32x4 wc0 = *(const f32x4*)(w1 + 512 + k0), wc1 = *(const f32x4*)(w1 + 512 + k0 + 4);
        f32x4 bb0 = *(const f32x4*)(b1 + k0),       bb1 = *(const f32x4*)(b1 + k0 + 4);
#pragma unroll
        for (int jj = 0; jj < 4; ++jj) {
            float v0 = fmaf(in0, wa0[jj], fmaf(in1, wb0[jj], fmaf(in2, wc0[jj], bb0[jj])));
            float v1 = fmaf(in0, wa1[jj], fmaf(in1, wb1[jj], fmaf(in2, wc1[jj], bb1[jj])));
            hv[c8][jj]     = f2bf(fmaxf(v0, 0.f));
            hv[c8][jj + 4] = f2bf(fmaxf(v1, 0.f));
        }
    }
    // phase-0: waves 0/1 write k<128 slice
    if (wave < 2) {
#pragma unroll
        for (int c8 = 0; c8 < 8; ++c8)
            *(short8*)(&Hh[lane * HSPLIT + wave * 64 + c8 * 8]) = hv[c8];
    }
    f32x4 b2q[4];
#pragma unroll
    for (int i = 0; i < 4; ++i)
        b2q[i] = *(const f32x4*)(b2v + wave * 64 + i * 16 + quad * 4);
    __syncthreads();   // drains phase-0 H writes (lgkm) + Wb(0) DMA (vmcnt)

    // --- H2^T MFMA loop ---
    f32x4 acc2[4][4];
#pragma unroll
    for (int i = 0; i < 4; ++i)
#pragma unroll
        for (int ms = 0; ms < 4; ++ms) acc2[i][ms] = (f32x4){0.f, 0.f, 0.f, 0.f};
#pragma unroll
    for (int s = 0; s < 8; ++s) {
        const int cur = s & 1;
        if (s < 7) stageW(cur ^ 1, s + 1);
        short8 wf[4], hf[4];
#pragma unroll
        for (int i = 0; i < 4; ++i)
            wf[i] = *(const short8*)(&Wb[cur][(quad * 256 + wave * 64 + i * 16 + ln16) * 8]);
        const int col = (s & 3) * 32 + quad * 8;    // k within current half
#pragma unroll
        for (int ms = 0; ms < 4; ++ms)
            hf[ms] = *(const short8*)(&Hh[(ms * 16 + ln16) * HSPLIT + col]);
#pragma unroll
        for (int i = 0; i < 4; ++i)
#pragma unroll
            for (int ms = 0; ms < 4; ++ms)
                acc2[i][ms] = __builtin_amdgcn_mfma_f32_16x16x32_bf16(wf[i], hf[ms], acc2[i][ms], 0, 0, 0);
        if (s == 3) {
            __syncthreads();          // drain DMA(4); all phase-0 H reads done
            if (wave >= 2) {          // phase-1: waves 2/3 write k>=128 slice
#pragma unroll
                for (int c8 = 0; c8 < 8; ++c8)
                    *(short8*)(&Hh[lane * HSPLIT + (wave - 2) * 64 + c8 * 8]) = hv[c8];
            }
            barrier_lds();            // phase-1 visible (lgkm only)
        } else if (s < 7) {
            __syncthreads();          // drain DMA(s+1)
        }
    }

    // --- F gather (late; wf/hf regs dead) ---
    const short* Fb = F + (long)b * 4096 * FROW;
    sv4 fv[4][4];
#pragma unroll
    for (int ms = 0; ms < 4; ++ms) {
        int linm = __shfl(lin, ms * 16 + ln16, 64);
        const short* Fr = Fb + (long)linm * FROW + wave * 64 + quad * 4;
#pragma unroll
        for (int i = 0; i < 4; ++i) fv[ms][i] = *(const sv4*)(Fr + i * 16);
    }
    const float fbv = bf2f(Fb[(long)lin * FROW + 256]);

    // --- combine: pred[m] += relu(H2[n][m]+b2[n]) * F[lin[m]][n] ---
    float part[4] = {0.f, 0.f, 0.f, 0.f};
#pragma unroll
    for (int i = 0; i < 4; ++i)
#pragma unroll
        for (int ms = 0; ms < 4; ++ms)
#pragma unroll
            for (int r = 0; r < 4; ++r)
                part[ms] = fmaf(fmaxf(acc2[i][ms][r] + b2q[i][r], 0.f), bf2f(fv[ms][i][r]), part[ms]);
#pragma unroll
    for (int ms = 0; ms < 4; ++ms) {
        part[ms] += __shfl_xor(part[ms], 16, 64);
        part[ms] += __shfl_xor(part[ms], 32, 64);
    }
    if (quad == 0) {
#pragma unroll
        for (int ms = 0; ms < 4; ++ms) red_s[ms * 16 + ln16][wave] = part[ms];
    }
    barrier_lds();
    if (t < 64)
        out[qbase + t] = red_s[t][0] + red_s[t][1] + red_s[t][2] + red_s[t][3] + fbv;
}

// ---------------------------------------------------------------------------
extern "C" void kernel_launch(void* const* d_in, const int* in_sizes, int n_in,
                              void* d_out, int out_size, void* d_ws, size_t ws_size,
                              hipStream_t stream) {
    const float* feat  = (const float*)d_in[0];
    const float* coord = (const float*)d_in[1];
    const float* cell  = (const float*)d_in[2];
    const float* w1    = (const float*)d_in[3];
    const float* b1    = (const float*)d_in[4];
    const float* w2    = (const float*)d_in[5];
    const float* b2    = (const float*)d_in[6];
    const float* w3    = (const float*)d_in[7];
    const float* b3    = (const float*)d_in[8];
    float* out = (float*)d_out;

    char* ws = (char*)d_ws;
    short* w3cB  = (short*)(ws);                       // 72*2176*2      = 313,344
    short* w2cB  = (short*)(ws + 313344);              // 32*2048*2      = 131,072
    short* featT = (short*)(ws + 444416);              // 16*66*66*64*2  = 8,921,088
    short* F     = (short*)(ws + 9365504);             // 16*4096*264*2  = 34,603,008
    (void)ws_size; (void)in_sizes; (void)n_in; (void)out_size;

    prep_transpose_k<<<BB * HT, 256, 0, stream>>>(feat, w2, w3, b3, featT, w3cB, w2cB);
    conv_k<<<BB * HH, 256, 0, stream>>>(featT, w3cB, F);
    mlp_k<<<(BB * QQ) / 64, 256, 0, stream>>>(coord, cell, w1, b1, b2, w2cB, F, out);
}